// Round 3
// baseline (545.890 us; speedup 1.0000x reference)
//
#include <hip/hip_runtime.h>
#include <hip/hip_bf16.h>

// VQ codebook lookup via split-bf16 MFMA + margin-based candidate recheck.
// x[16,256,32,32] f32, E[256,8192] f32, N=16384 tokens, K=8192 codes.
// S = (xh+xl).eh via 2 bf16 MFMAs; dist = c_k - 2S; dist error std ~1.1e-3.
// MARGIN 0.02 ~ 13 sigma of pairwise error difference. Flagged tokens:
// block top-1s in window -> exact pair recheck; blocks with top-2 in window
// -> exact 256-code BLOCK scan (covers any rank in that block).
// Exact path = ascending-d fmaf chain (validated vs numpy R1-R8).
// Staging: conflict-free XOR-swizzled global_load_lds (R6/R7-verified).
//
// R12: counted-vmcnt schedule (T3+T4+T5) replacing the 2-barrier drain loop
//   whose vmcnt(0)-per-step stall pinned MfmaUtil at 28% across R9/R10/R11:
//   - 8 waves (512 thr), BM=128, BN=256, BK=32. A planes [8db][128][32]
//     fully LDS-resident, each db region written once (step db-1) / read
//     once (step db) -> no A buffering. B double-buffered. LDS = 160 KiB.
//   - per step: issue 4 loads (A hi/lo + 2xB for t+1), s_waitcnt vmcnt(4)
//     (waits prev step's 4 only, new 4 stay in flight across the barrier),
//     raw s_barrier, setprio(1) MFMA cluster setprio(0), raw s_barrier.
//     No vmcnt(0) drain in the loop (only final step).
//   - XCD both-operand residency: xcd=bid&7 owns mb in [xcd*16,xcd*16+16)
//     (2MB xh/xl slice L2-resident), nb slow (128KB eh slice resident).
// Downstream kernels and pd1/pi1/pd2 layout unchanged.

#define D_   256
#define HW_  1024
#define N_   16384
#define K_   8192
#define NB_  32              // 32 code-blocks of 256
#define MARGIN 0.02f         // ~13 sigma of approx-error difference

#define OUT1_OFF 4194304     // B*D*H*W
#define IND_OFF  8388608

typedef __attribute__((ext_vector_type(8))) short bf16x8;   // 8 bf16 = 4 VGPR
typedef __attribute__((ext_vector_type(4))) float f32x4;

__device__ __forceinline__ unsigned long long pack_dk(float dist, int k) {
    unsigned db = __float_as_uint(dist);
    unsigned mono = (db & 0x80000000u) ? ~db : (db | 0x80000000u);
    return ((unsigned long long)mono << 32) | (unsigned)k;
}

// async global->LDS DMA: lane i of the wave lands at ldsbase + 16*i.
__device__ __forceinline__ void async_copy16(const void* g, void* l) {
    __builtin_amdgcn_global_load_lds(
        (const __attribute__((address_space(1))) void*)g,
        (__attribute__((address_space(3))) void*)l, 16, 0, 0);
}

// ---------------- codebook column norms + counter zeroing -------------------
__global__ __launch_bounds__(256)
void cnorm_kernel(const float* __restrict__ E, float* __restrict__ c,
                  int* __restrict__ counters) {
    if (blockIdx.x == 0 && threadIdx.x < 2) counters[threadIdx.x] = 0;
    __shared__ float part[8][32];
    const int tid = threadIdx.x;
    const int cl = tid & 31, q = tid >> 5;
    const int k = blockIdx.x * 32 + cl;
    float s = 0.f;
    #pragma unroll 8
    for (int d = q * 32; d < q * 32 + 32; ++d) {
        float v = E[(size_t)d * K_ + k];
        s = fmaf(v, v, s);
    }
    part[q][cl] = s;
    __syncthreads();
    if (tid < 32) {   // fixed combine order: deterministic
        float t0 = (part[0][tid] + part[1][tid]) + (part[2][tid] + part[3][tid]);
        float t1 = (part[4][tid] + part[5][tid]) + (part[6][tid] + part[7][tid]);
        c[blockIdx.x * 32 + tid] = t0 + t1;
    }
}

// ---------------- prep: split x fp32 -> (hi,lo) bf16 planes, transposed -----
__global__ __launch_bounds__(256)
void prep_x(const float* __restrict__ x, ushort* __restrict__ xh, ushort* __restrict__ xl) {
    __shared__ float t[32][33];
    const int s0 = blockIdx.x * 32, d0 = blockIdx.y * 32, b = blockIdx.z;
    const int tid = threadIdx.x;
    #pragma unroll
    for (int j = 0; j < 4; ++j) {
        int i = tid + 256 * j; int dd = i >> 5, ss = i & 31;
        t[dd][ss] = x[(size_t)b * 262144 + (size_t)(d0 + dd) * 1024 + s0 + ss];
    }
    __syncthreads();
    #pragma unroll
    for (int j = 0; j < 4; ++j) {
        int i = tid + 256 * j; int ss = i >> 5, dd = i & 31;
        float v = t[dd][ss];
        __hip_bfloat16 h = __float2bfloat16(v);
        float r = v - __bfloat162float(h);
        __hip_bfloat16 l = __float2bfloat16(r);
        size_t o = (size_t)(b * 1024 + s0 + ss) * D_ + d0 + dd;
        xh[o] = *(ushort*)&h;
        xl[o] = *(ushort*)&l;
    }
}

// E[d][k] -> eh[k][d] (hi plane only)
__global__ __launch_bounds__(256)
void prep_e(const float* __restrict__ E, ushort* __restrict__ eh) {
    __shared__ float t[32][33];
    const int k0 = blockIdx.x * 32, d0 = blockIdx.y * 32;
    const int tid = threadIdx.x;
    #pragma unroll
    for (int j = 0; j < 4; ++j) {
        int i = tid + 256 * j; int dd = i >> 5, kk = i & 31;
        t[dd][kk] = E[(size_t)(d0 + dd) * K_ + k0 + kk];
    }
    __syncthreads();
    #pragma unroll
    for (int j = 0; j < 4; ++j) {
        int i = tid + 256 * j; int kk = i >> 5, dd = i & 31;
        __hip_bfloat16 h = __float2bfloat16(t[dd][kk]);
        eh[(size_t)(k0 + kk) * D_ + d0 + dd] = *(ushort*)&h;
    }
}

// ---------------- MFMA distance + per-token top-2 per 256-code block --------
// grid 4096 flat, XCD-partitioned. 512 threads = 8 waves (wy 0..1 x wx 0..3),
// wave tile 64 tokens x 64 codes (acc 4x4). A [8][128][32] per plane fully
// LDS-resident (progressive stream); B [2][256][32] dbuf. Counted vmcnt(4),
// raw barriers, setprio around MFMA. LDS rows = 64B of 4x16B chunks, chunk
// position = chunk ^ ((row>>1)&3) — conflict-free both directions (verified).
__global__ __launch_bounds__(512, 2)
void mfma_kernel(const ushort* __restrict__ xh, const ushort* __restrict__ xl,
                 const ushort* __restrict__ eh,
                 const float* __restrict__ c,
                 float* __restrict__ pd1, int* __restrict__ pi1, float* __restrict__ pd2) {
    __shared__ __align__(16) ushort lds[81920];   // 160 KiB exact
    ushort* Ah = lds;                              // [8][128][32]
    ushort* Al = lds + 32768;                      // [8][128][32]
    ushort* Bb = lds + 65536;                      // [2][256][32]

    const int tid = threadIdx.x;
    // XCD partition: xcd owns mb in [xcd*16, xcd*16+16); nb slow within xcd.
    const int bid = blockIdx.x;
    const int xcd = bid & 7, rr = bid >> 3;
    const int nb = rr >> 4, mb = xcd * 16 + (rr & 15);
    const int n0 = mb * 128, k0 = nb * 256;
    const int lane = tid & 63, w = tid >> 6;
    const int wy = w >> 2, wx = w & 3;
    const int l15 = lane & 15, lq = lane >> 4;

    // A staging: 1 load per wave per plane per db (512 slots = 8 waves x 64)
    size_t aoff;
    {
        int slot = w * 64 + lane;
        int t = slot >> 2, cp = slot & 3;
        int cs = cp ^ ((t >> 1) & 3);
        aoff = (size_t)(n0 + t) * D_ + cs * 8;
    }
    const int adst = w * 512;          // ushort offset within a db region (4096)
    // B staging: 2 loads per wave per step (1024 slots)
    size_t boff[2]; int bdst[2];
    #pragma unroll
    for (int g = 0; g < 2; ++g) {
        int slot = (w * 2 + g) * 64 + lane;
        int t = slot >> 2, cp = slot & 3;
        int cs = cp ^ ((t >> 1) & 3);
        boff[g] = (size_t)(k0 + t) * D_ + cs * 8;
        bdst[g] = (w * 2 + g) * 512;
    }
    // fragment read offsets
    int aro[4], bro[4];
    #pragma unroll
    for (int mt = 0; mt < 4; ++mt) {
        int R = wy * 64 + mt * 16 + l15;
        aro[mt] = R * 32 + ((lq ^ ((R >> 1) & 3)) * 8);
    }
    #pragma unroll
    for (int nt = 0; nt < 4; ++nt) {
        int R = wx * 64 + nt * 16 + l15;
        bro[nt] = R * 32 + ((lq ^ ((R >> 1) & 3)) * 8);
    }

    f32x4 acc[4][4];
    #pragma unroll
    for (int mt = 0; mt < 4; ++mt)
        #pragma unroll
        for (int nt = 0; nt < 4; ++nt) acc[mt][nt] = (f32x4){0.f, 0.f, 0.f, 0.f};

    // prologue: stage A[0] + B[0]  (4 loads/wave outstanding)
    async_copy16(xh + aoff, &Ah[adst]);
    async_copy16(xl + aoff, &Al[adst]);
    #pragma unroll
    for (int g = 0; g < 2; ++g)
        async_copy16(eh + boff[g], &Bb[bdst[g]]);

    #pragma unroll
    for (int db = 0; db < 8; ++db) {
        const int cur = db & 1;
        if (db < 7) {
            // issue step db+1's 4 loads, then wait only for step db's 4:
            // the new 4 stay in flight across the barrier (counted vmcnt).
            const int dn = (db + 1) * 32;
            async_copy16(xh + aoff + dn, &Ah[(db + 1) * 4096 + adst]);
            async_copy16(xl + aoff + dn, &Al[(db + 1) * 4096 + adst]);
            #pragma unroll
            for (int g = 0; g < 2; ++g)
                async_copy16(eh + boff[g] + dn, &Bb[(cur ^ 1) * 8192 + bdst[g]]);
            asm volatile("s_waitcnt vmcnt(4)" ::: "memory");
        } else {
            asm volatile("s_waitcnt vmcnt(0)" ::: "memory");
        }
        asm volatile("s_barrier" ::: "memory");   // all waves passed their gate
        __builtin_amdgcn_s_setprio(1);
        bf16x8 a_h[4], a_l[4];
        #pragma unroll
        for (int mt = 0; mt < 4; ++mt) {
            a_h[mt] = *(const bf16x8*)&Ah[db * 4096 + aro[mt]];
            a_l[mt] = *(const bf16x8*)&Al[db * 4096 + aro[mt]];
        }
        #pragma unroll
        for (int nt = 0; nt < 4; ++nt) {
            bf16x8 b_h = *(const bf16x8*)&Bb[cur * 8192 + bro[nt]];
            #pragma unroll
            for (int mt = 0; mt < 4; ++mt) {
                acc[mt][nt] = __builtin_amdgcn_mfma_f32_16x16x32_bf16(a_h[mt], b_h, acc[mt][nt], 0, 0, 0);
                acc[mt][nt] = __builtin_amdgcn_mfma_f32_16x16x32_bf16(a_l[mt], b_h, acc[mt][nt], 0, 0, 0);
            }
        }
        __builtin_amdgcn_s_setprio(0);
        asm volatile("s_barrier" ::: "memory");   // protect B[cur] from t+2 writes
    }

    float cv[4];
    #pragma unroll
    for (int nt = 0; nt < 4; ++nt) cv[nt] = c[k0 + wx * 64 + nt * 16 + l15];

    float m1[16], m2[16]; int i1[16];
    #pragma unroll
    for (int mt = 0; mt < 4; ++mt)
        #pragma unroll
        for (int r = 0; r < 4; ++r) {
            int p = mt * 4 + r;
            float a = 3.4e38f, b2 = 3.4e38f; int ai = -1;
            #pragma unroll
            for (int nt = 0; nt < 4; ++nt) {
                float d = fmaf(-2.f, acc[mt][nt][r], cv[nt]);
                int k = k0 + wx * 64 + nt * 16 + l15;
                if (d < a) { b2 = a; a = d; ai = k; } else if (d < b2) b2 = d;
            }
            m1[p] = a; i1[p] = ai; m2[p] = b2;
        }
    #pragma unroll
    for (int s = 1; s < 16; s <<= 1) {
        #pragma unroll
        for (int p = 0; p < 16; ++p) {
            float n1 = __shfl_xor(m1[p], s);
            int   ni = __shfl_xor(i1[p], s);
            float n2 = __shfl_xor(m2[p], s);
            if (n1 < m1[p]) { m2[p] = fminf(m1[p], n2); m1[p] = n1; i1[p] = ni; }
            else            { m2[p] = fminf(m2[p], n1); }
        }
    }
    // reduction arrays overlay the B buffers (dead after the loop). [128][5]
    // padding -> conflict-free combine reads.
    float* redm1 = (float*)Bb;            // 2560 B
    float* redm2 = redm1 + 640;           // 2560 B
    int*   redi1 = (int*)(redm2 + 640);   // 2560 B
    if (l15 == 0) {
        #pragma unroll
        for (int mt = 0; mt < 4; ++mt)
            #pragma unroll
            for (int r = 0; r < 4; ++r) {
                int p = mt * 4 + r;
                int t = wy * 64 + mt * 16 + lq * 4 + r;
                redm1[t * 5 + wx] = m1[p]; redi1[t * 5 + wx] = i1[p]; redm2[t * 5 + wx] = m2[p];
            }
    }
    __syncthreads();
    if (tid < 128) {   // fixed combine order wx=0..3: deterministic
        float a = redm1[tid * 5], b2 = redm2[tid * 5]; int ai = redi1[tid * 5];
        #pragma unroll
        for (int q = 1; q < 4; ++q) {
            float n1 = redm1[tid * 5 + q], n2 = redm2[tid * 5 + q]; int ni = redi1[tid * 5 + q];
            if (n1 < a) { b2 = fminf(a, n2); a = n1; ai = ni; }
            else        { b2 = fminf(b2, n1); }
        }
        size_t o = (size_t)nb * N_ + n0 + tid;
        pd1[o] = a; pi1[o] = ai; pd2[o] = b2;
    }
}

// ---------------- merge 32 blocks; enumerate pair/scan candidates -----------
// counters[0]=pairs, [1]=block-scan tasks. Coverage: true winner j in block B
// is B's top-1 (pd1<=W -> pair) or has obs >= pd2_B, forcing pd2_B<=W -> B
// gets an exact 256-code scan which covers ANY rank in B.
__global__ __launch_bounds__(256)
void merge_flag(const float* __restrict__ pd1, const int* __restrict__ pi1,
                const float* __restrict__ pd2,
                int* __restrict__ idx, int* __restrict__ counters,
                unsigned long long* __restrict__ key,
                unsigned int* __restrict__ pairs, unsigned int* __restrict__ scans) {
    int n = blockIdx.x * 256 + threadIdx.x;
    float a = 3.4e38f, b2 = 3.4e38f; int ai = -1;
    for (int nb = 0; nb < NB_; ++nb) {
        float n1 = pd1[(size_t)nb * N_ + n];
        int   ni = pi1[(size_t)nb * N_ + n];
        float n2 = pd2[(size_t)nb * N_ + n];
        if (n1 < a) { b2 = fminf(a, n2); a = n1; ai = ni; }
        else        { b2 = fminf(b2, n1); }
    }
    if (b2 - a < MARGIN) {
        const float W = a + MARGIN;
        key[n] = ~0ULL;
        idx[n] = 0x80000000 | ai;          // flagged: resolve from key later
        for (int nb = 0; nb < NB_; ++nb) {
            if (pd2[(size_t)nb * N_ + n] <= W) {
                int q = atomicAdd(&counters[1], 1);
                scans[q] = ((unsigned)n << 5) | (unsigned)nb;
            } else if (pd1[(size_t)nb * N_ + n] <= W) {
                int q = atomicAdd(&counters[0], 1);
                pairs[q] = ((unsigned)n << 13) | (unsigned)pi1[(size_t)nb * N_ + n];
            }
        }
    } else {
        idx[n] = ai;
    }
}

// ---------------- fused exact fp32 recheck (pairs + block scans) ------------
// blocks [0,128): 4 threads per (token, candidate); blocks [128,384): one
// (token, 256-code block) exact scan per task, E rows coalesced.
__global__ __launch_bounds__(256)
void recheck(const float* __restrict__ x, const float* __restrict__ E,
             const float* __restrict__ c, const unsigned int* __restrict__ pairs,
             const unsigned int* __restrict__ scans, const int* __restrict__ counters,
             unsigned long long* __restrict__ key) {
    if (blockIdx.x < 128) {
        int items = counters[0] * 4;
        for (int it = blockIdx.x * 256 + threadIdx.x; it < items; it += 128 * 256) {
            int p = it >> 2, q = it & 3;   // quads stay intact: stride % 4 == 0
            unsigned v = pairs[p];
            int n = v >> 13, k = v & 8191;
            int b = n >> 10, s = n & 1023;
            const float* xb = x + (size_t)b * 262144 + s;
            const float* eb = E + k;
            float acc = 0.f;
            const int d0 = q * 64;
            #pragma unroll 8
            for (int d = d0; d < d0 + 64; ++d)
                acc = fmaf(xb[(size_t)d * HW_], eb[(size_t)d * K_], acc);
            float o1 = __shfl_xor(acc, 1); float s2 = acc + o1;
            float o2 = __shfl_xor(s2, 2);  float tot = s2 + o2;   // ((q0+q1)+(q2+q3))
            if (q == 0) atomicMin(key + n, pack_dk(fmaf(-2.f, tot, c[k]), k));
        }
    } else {
        int cnt = counters[1];
        for (int t = blockIdx.x - 128; t < cnt; t += 256) {
            unsigned v = scans[t];
            int n = v >> 5, nb = v & 31;
            int k = nb * 256 + threadIdx.x;
            int b = n >> 10, s = n & 1023;
            const float* xb = x + (size_t)b * 262144 + s;
            float acc = 0.f;
            #pragma unroll 4
            for (int d = 0; d < D_; ++d)          // ascending d: exact ref chain
                acc = fmaf(xb[(size_t)d * HW_], E[(size_t)d * K_ + k], acc);
            float dist = fmaf(-2.f, acc, c[k]);
            atomicMin(key + n, pack_dk(dist, k));  // (dist,k) lex-min: first-min ties
        }
    }
}

// ---------------- gather + write outputs (float4, fixup via sign bit) -------
__global__ __launch_bounds__(256)
void write_kernel(const float* __restrict__ x, const float* __restrict__ E,
                  const int* __restrict__ idx, const unsigned long long* __restrict__ key,
                  float* __restrict__ out) {
    __shared__ int kst[64];
    const int n0 = blockIdx.x * 64;
    const int b = n0 >> 10, s0 = n0 & 1023;
    const int tid = threadIdx.x;
    if (tid < 64) {
        int v = idx[n0 + tid];
        int k = (v < 0) ? (int)(key[n0 + tid] & 8191ULL) : v;
        kst[tid] = k;
        out[IND_OFF + n0 + tid] = (float)k;
    }
    __syncthreads();
    const int g = tid & 15;               // float4 group of 4 tokens
    const int d0 = tid >> 4;              // 16 d-streams
    const int ka = kst[g * 4], kb2 = kst[g * 4 + 1], kc = kst[g * 4 + 2], kd = kst[g * 4 + 3];
    const float* xb = x + (size_t)b * 262144 + s0 + g * 4;
    float* o0 = out + (size_t)b * 262144 + s0 + g * 4;
    float* o1 = o0 + OUT1_OFF;
    for (int d = d0; d < D_; d += 16) {
        const float* er = E + (size_t)d * K_;
        float4 xv = *(const float4*)(xb + (size_t)d * HW_);
        float4 q;
        q.x = er[ka]; q.y = er[kb2]; q.z = er[kc]; q.w = er[kd];
        float4 r;                          // x + (q - x): replicate jnp fp32 rounding
        r.x = xv.x + (q.x - xv.x); r.y = xv.y + (q.y - xv.y);
        r.z = xv.z + (q.z - xv.z); r.w = xv.w + (q.w - xv.w);
        *(float4*)(o0 + (size_t)d * HW_) = r;
        *(float4*)(o1 + (size_t)d * HW_) = q;
    }
}

extern "C" void kernel_launch(void* const* d_in, const int* in_sizes, int n_in,
                              void* d_out, int out_size, void* d_ws, size_t ws_size,
                              hipStream_t stream) {
    const float* x = (const float*)d_in[0];
    const float* E = (const float*)d_in[1];
    float* out = (float*)d_out;

    char* p = (char*)d_ws;
    ushort* xh = (ushort*)p;                 p += (size_t)N_ * D_ * 2;   // 8 MB
    ushort* xl = (ushort*)p;                 p += (size_t)N_ * D_ * 2;   // 8 MB
    ushort* eh = (ushort*)p;                 p += (size_t)K_ * D_ * 2;   // 4 MB
    float*  c  = (float*)p;                  p += (size_t)K_ * 4;
    float*  pd1 = (float*)p;                 p += (size_t)NB_ * N_ * 4;  // 2 MB
    int*    pi1 = (int*)p;                   p += (size_t)NB_ * N_ * 4;
    float*  pd2 = (float*)p;                 p += (size_t)NB_ * N_ * 4;
    int*    idx = (int*)p;                   p += (size_t)N_ * 4;
    unsigned long long* key = (unsigned long long*)p; p += (size_t)N_ * 8;
    unsigned int* pairs = (unsigned int*)p;  p += (size_t)524288 * 4;    // 2 MB cap
    unsigned int* scans = (unsigned int*)p;  p += (size_t)524288 * 4;    // 2 MB cap
    int*    counters = (int*)p;              p += 256;

    cnorm_kernel<<<K_ / 32, 256, 0, stream>>>(E, c, counters);
    prep_x<<<dim3(32, 8, 16), 256, 0, stream>>>(x, xh, xl);
    prep_e<<<dim3(256, 8), 256, 0, stream>>>(E, eh);
    mfma_kernel<<<4096, 512, 0, stream>>>(xh, xl, eh, c, pd1, pi1, pd2);
    merge_flag<<<N_ / 256, 256, 0, stream>>>(pd1, pi1, pd2, idx, counters, key, pairs, scans);
    recheck<<<384, 256, 0, stream>>>(x, E, c, pairs, scans, counters, key);
    write_kernel<<<N_ / 64, 256, 0, stream>>>(x, E, idx, key, out);
}

// Round 4
// 411.932 us; speedup vs baseline: 1.3252x; 1.3252x over previous
//
#include <hip/hip_runtime.h>
#include <hip/hip_bf16.h>

// VQ codebook lookup via split-bf16 MFMA + margin-based candidate recheck.
// x[16,256,32,32] f32, E[256,8192] f32, N=16384 tokens, K=8192 codes.
// S = (xh+xl).eh via 2 bf16 MFMAs; dist = c_k - 2S; dist error std ~1.1e-3.
// MARGIN 0.02 ~ 13 sigma of pairwise error difference. Flagged tokens:
// block top-1s in window -> exact pair recheck; blocks with top-2 in window
// -> exact 256-code BLOCK scan (covers any rank in that block).
// Exact path = ascending-d fmaf chain (validated vs numpy R1-R8).
// Staging: conflict-free XOR-swizzled global_load_lds (R6/R7-verified).
//
// R13: revert R12's counted-vmcnt/1-block-per-CU structure (15% MfmaUtil —
//   barrier-lockstep convoy with no cross-block cover). Back to the proven
//   2-phase dbuf skeleton (R10), with the convoy inputs reduced:
//   - A-lo plane no longer staged in LDS: each wave's a_l fragment is 8
//     contiguous bf16 in token-major xl -> one global_load_dwordx4 direct
//     to regs per fragment (L2-resident via XCD partition). Deletes 2
//     gload_lds + 4 ds_reads + 8KB LDS per step; ds:MFMA 12:32 -> 8:32.
//     Per-acc chain stays hi(db),lo(db) -> bit-identical numerics.
//   - block 4 waves, tile 64 tok x 256 codes, wave 64x64 (acc[4][4]=64
//     AGPR) -> ~160 regs = 3 waves/SIMD; LDS 45KB -> 3 blocks/CU (3
//     independent barrier domains).
//   - XCD both-operand residency kept from R12 (FETCH 25MB proved it):
//     xcd=bid&7 owns mb in [xcd*32,xcd*32+32), nb slow; 2.1MB/XCD hot.
// Downstream kernels and pd1/pi1/pd2 layout unchanged.

#define D_   256
#define HW_  1024
#define N_   16384
#define K_   8192
#define NB_  32              // 32 code-blocks of 256
#define MARGIN 0.02f         // ~13 sigma of approx-error difference

#define OUT1_OFF 4194304     // B*D*H*W
#define IND_OFF  8388608

typedef __attribute__((ext_vector_type(8))) short bf16x8;   // 8 bf16 = 4 VGPR
typedef __attribute__((ext_vector_type(4))) float f32x4;

__device__ __forceinline__ unsigned long long pack_dk(float dist, int k) {
    unsigned db = __float_as_uint(dist);
    unsigned mono = (db & 0x80000000u) ? ~db : (db | 0x80000000u);
    return ((unsigned long long)mono << 32) | (unsigned)k;
}

// async global->LDS DMA: lane i of the wave lands at ldsbase + 16*i.
__device__ __forceinline__ void async_copy16(const void* g, void* l) {
    __builtin_amdgcn_global_load_lds(
        (const __attribute__((address_space(1))) void*)g,
        (__attribute__((address_space(3))) void*)l, 16, 0, 0);
}

// ---------------- codebook column norms + counter zeroing -------------------
__global__ __launch_bounds__(256)
void cnorm_kernel(const float* __restrict__ E, float* __restrict__ c,
                  int* __restrict__ counters) {
    if (blockIdx.x == 0 && threadIdx.x < 2) counters[threadIdx.x] = 0;
    __shared__ float part[8][32];
    const int tid = threadIdx.x;
    const int cl = tid & 31, q = tid >> 5;
    const int k = blockIdx.x * 32 + cl;
    float s = 0.f;
    #pragma unroll 8
    for (int d = q * 32; d < q * 32 + 32; ++d) {
        float v = E[(size_t)d * K_ + k];
        s = fmaf(v, v, s);
    }
    part[q][cl] = s;
    __syncthreads();
    if (tid < 32) {   // fixed combine order: deterministic
        float t0 = (part[0][tid] + part[1][tid]) + (part[2][tid] + part[3][tid]);
        float t1 = (part[4][tid] + part[5][tid]) + (part[6][tid] + part[7][tid]);
        c[blockIdx.x * 32 + tid] = t0 + t1;
    }
}

// ---------------- prep: split x fp32 -> (hi,lo) bf16 planes, transposed -----
__global__ __launch_bounds__(256)
void prep_x(const float* __restrict__ x, ushort* __restrict__ xh, ushort* __restrict__ xl) {
    __shared__ float t[32][33];
    const int s0 = blockIdx.x * 32, d0 = blockIdx.y * 32, b = blockIdx.z;
    const int tid = threadIdx.x;
    #pragma unroll
    for (int j = 0; j < 4; ++j) {
        int i = tid + 256 * j; int dd = i >> 5, ss = i & 31;
        t[dd][ss] = x[(size_t)b * 262144 + (size_t)(d0 + dd) * 1024 + s0 + ss];
    }
    __syncthreads();
    #pragma unroll
    for (int j = 0; j < 4; ++j) {
        int i = tid + 256 * j; int ss = i >> 5, dd = i & 31;
        float v = t[dd][ss];
        __hip_bfloat16 h = __float2bfloat16(v);
        float r = v - __bfloat162float(h);
        __hip_bfloat16 l = __float2bfloat16(r);
        size_t o = (size_t)(b * 1024 + s0 + ss) * D_ + d0 + dd;
        xh[o] = *(ushort*)&h;
        xl[o] = *(ushort*)&l;
    }
}

// E[d][k] -> eh[k][d] (hi plane only)
__global__ __launch_bounds__(256)
void prep_e(const float* __restrict__ E, ushort* __restrict__ eh) {
    __shared__ float t[32][33];
    const int k0 = blockIdx.x * 32, d0 = blockIdx.y * 32;
    const int tid = threadIdx.x;
    #pragma unroll
    for (int j = 0; j < 4; ++j) {
        int i = tid + 256 * j; int dd = i >> 5, kk = i & 31;
        t[dd][kk] = E[(size_t)(d0 + dd) * K_ + k0 + kk];
    }
    __syncthreads();
    #pragma unroll
    for (int j = 0; j < 4; ++j) {
        int i = tid + 256 * j; int kk = i >> 5, dd = i & 31;
        __hip_bfloat16 h = __float2bfloat16(t[dd][kk]);
        eh[(size_t)(k0 + kk) * D_ + d0 + dd] = *(ushort*)&h;
    }
}

// ---------------- MFMA distance + per-token top-2 per 256-code block --------
// grid 8192 flat, XCD-partitioned. block 256 = 4 waves (wx = w), block tile
// 64 tokens x 256 codes, wave tile 64x64 (acc[4][4]). 2-phase dbuf, prefetch
// t+1 before compute of t, one __syncthreads per step. A-lo direct from
// global to regs. LDS rows = 64B of 4x16B chunks, chunk position =
// chunk ^ ((row>>1)&3) — conflict-free both directions (verified).
__global__ __launch_bounds__(256, 3)
void mfma_kernel(const ushort* __restrict__ xh, const ushort* __restrict__ xl,
                 const ushort* __restrict__ eh,
                 const float* __restrict__ c,
                 float* __restrict__ pd1, int* __restrict__ pi1, float* __restrict__ pd2) {
    __shared__ __align__(16) ushort Ah[2][2048];   // [2][64*32]  8 KB
    __shared__ __align__(16) ushort Bb[2][8192];   // [2][256*32] 32 KB
    __shared__ float redm1[320], redm2[320];       // [64][5] padded
    __shared__ int   redi1[320];

    const int tid = threadIdx.x;
    // XCD partition: xcd owns mb in [xcd*32, xcd*32+32); nb slow within xcd.
    const int bid = blockIdx.x;
    const int xcd = bid & 7, rr = bid >> 3;
    const int nb = rr >> 5, mb = xcd * 32 + (rr & 31);
    const int n0 = mb * 64, k0 = nb * 256;
    const int lane = tid & 63, w = tid >> 6;       // w = code quadrant 0..3
    const int l15 = lane & 15, lq = lane >> 4;

    // A staging: 1 gload_lds per wave per step (4 waves cover 64 rows)
    size_t aoff;
    {
        int slot = w * 64 + lane;
        int t = slot >> 2, cp = slot & 3;
        int cs = cp ^ ((t >> 1) & 3);
        aoff = (size_t)(n0 + t) * D_ + cs * 8;
    }
    const int adst = w * 512;                      // ushort offset
    // B staging: 4 gload_lds per wave per step
    size_t boff[4]; int bdst[4];
    #pragma unroll
    for (int g = 0; g < 4; ++g) {
        int slot = (w * 4 + g) * 64 + lane;
        int t = slot >> 2, cp = slot & 3;
        int cs = cp ^ ((t >> 1) & 3);
        boff[g] = (size_t)(k0 + t) * D_ + cs * 8;
        bdst[g] = (w * 4 + g) * 512;
    }
    // fragment read offsets (XOR matches staging swizzle)
    int aro[4], bro[4];
    #pragma unroll
    for (int mt = 0; mt < 4; ++mt) {
        int R = mt * 16 + l15;
        aro[mt] = R * 32 + ((lq ^ ((R >> 1) & 3)) * 8);
    }
    #pragma unroll
    for (int nt = 0; nt < 4; ++nt) {
        int R = w * 64 + nt * 16 + l15;
        bro[nt] = R * 32 + ((lq ^ ((R >> 1) & 3)) * 8);
    }
    // a_lo direct-global fragment bases (token-major xl, 16B aligned)
    const ushort* alo[4];
    #pragma unroll
    for (int mt = 0; mt < 4; ++mt)
        alo[mt] = xl + (size_t)(n0 + mt * 16 + l15) * D_ + lq * 8;

    f32x4 acc[4][4];
    #pragma unroll
    for (int mt = 0; mt < 4; ++mt)
        #pragma unroll
        for (int nt = 0; nt < 4; ++nt) acc[mt][nt] = (f32x4){0.f, 0.f, 0.f, 0.f};

    // prologue: stage step 0 into buffer 0
    async_copy16(xh + aoff, &Ah[0][adst]);
    #pragma unroll
    for (int g = 0; g < 4; ++g)
        async_copy16(eh + boff[g], &Bb[0][bdst[g]]);
    __syncthreads();

    #pragma unroll
    for (int db = 0; db < 8; ++db) {
        const int cur = db & 1;
        const int d0 = db * 32;
        // a_lo for THIS step: direct global->reg (consumed after hi pass,
        // ~600 cyc of cover; L2-resident slice)
        bf16x8 a_l[4];
        #pragma unroll
        for (int mt = 0; mt < 4; ++mt)
            a_l[mt] = *(const bf16x8*)(alo[mt] + d0);
        if (db < 7) {   // prefetch step t+1 into the other buffer
            const int dn = d0 + 32;
            async_copy16(xh + aoff + dn, &Ah[cur ^ 1][adst]);
            #pragma unroll
            for (int g = 0; g < 4; ++g)
                async_copy16(eh + boff[g] + dn, &Bb[cur ^ 1][bdst[g]]);
        }
        bf16x8 a_h[4], b[4];
        #pragma unroll
        for (int mt = 0; mt < 4; ++mt)
            a_h[mt] = *(const bf16x8*)&Ah[cur][aro[mt]];
        #pragma unroll
        for (int nt = 0; nt < 4; ++nt)
            b[nt] = *(const bf16x8*)&Bb[cur][bro[nt]];
        // hi pass then lo pass: per-acc call chain stays hi(db),lo(db) —
        // bit-identical to the validated interleaved order.
        #pragma unroll
        for (int nt = 0; nt < 4; ++nt)
            #pragma unroll
            for (int mt = 0; mt < 4; ++mt)
                acc[mt][nt] = __builtin_amdgcn_mfma_f32_16x16x32_bf16(a_h[mt], b[nt], acc[mt][nt], 0, 0, 0);
        #pragma unroll
        for (int nt = 0; nt < 4; ++nt)
            #pragma unroll
            for (int mt = 0; mt < 4; ++mt)
                acc[mt][nt] = __builtin_amdgcn_mfma_f32_16x16x32_bf16(a_l[mt], b[nt], acc[mt][nt], 0, 0, 0);
        __syncthreads();   // drains prefetch; protects buffer reuse
    }

    float cv[4];
    #pragma unroll
    for (int nt = 0; nt < 4; ++nt) cv[nt] = c[k0 + w * 64 + nt * 16 + l15];

    float m1[16], m2[16]; int i1[16];
    #pragma unroll
    for (int mt = 0; mt < 4; ++mt)
        #pragma unroll
        for (int r = 0; r < 4; ++r) {
            int p = mt * 4 + r;
            float a = 3.4e38f, b2 = 3.4e38f; int ai = -1;
            #pragma unroll
            for (int nt = 0; nt < 4; ++nt) {
                float d = fmaf(-2.f, acc[mt][nt][r], cv[nt]);
                int k = k0 + w * 64 + nt * 16 + l15;
                if (d < a) { b2 = a; a = d; ai = k; } else if (d < b2) b2 = d;
            }
            m1[p] = a; i1[p] = ai; m2[p] = b2;
        }
    #pragma unroll
    for (int s = 1; s < 16; s <<= 1) {
        #pragma unroll
        for (int p = 0; p < 16; ++p) {
            float n1 = __shfl_xor(m1[p], s);
            int   ni = __shfl_xor(i1[p], s);
            float n2 = __shfl_xor(m2[p], s);
            if (n1 < m1[p]) { m2[p] = fminf(m1[p], n2); m1[p] = n1; i1[p] = ni; }
            else            { m2[p] = fminf(m2[p], n1); }
        }
    }
    if (l15 == 0) {
        #pragma unroll
        for (int mt = 0; mt < 4; ++mt)
            #pragma unroll
            for (int r = 0; r < 4; ++r) {
                int p = mt * 4 + r;
                int t = mt * 16 + lq * 4 + r;
                redm1[t * 5 + w] = m1[p]; redi1[t * 5 + w] = i1[p]; redm2[t * 5 + w] = m2[p];
            }
    }
    __syncthreads();
    if (tid < 64) {   // fixed combine order w=0..3: deterministic
        float a = redm1[tid * 5], b2 = redm2[tid * 5]; int ai = redi1[tid * 5];
        #pragma unroll
        for (int q = 1; q < 4; ++q) {
            float n1 = redm1[tid * 5 + q], n2 = redm2[tid * 5 + q]; int ni = redi1[tid * 5 + q];
            if (n1 < a) { b2 = fminf(a, n2); a = n1; ai = ni; }
            else        { b2 = fminf(b2, n1); }
        }
        size_t o = (size_t)nb * N_ + n0 + tid;
        pd1[o] = a; pi1[o] = ai; pd2[o] = b2;
    }
}

// ---------------- merge 32 blocks; enumerate pair/scan candidates -----------
// counters[0]=pairs, [1]=block-scan tasks. Coverage: true winner j in block B
// is B's top-1 (pd1<=W -> pair) or has obs >= pd2_B, forcing pd2_B<=W -> B
// gets an exact 256-code scan which covers ANY rank in B.
__global__ __launch_bounds__(256)
void merge_flag(const float* __restrict__ pd1, const int* __restrict__ pi1,
                const float* __restrict__ pd2,
                int* __restrict__ idx, int* __restrict__ counters,
                unsigned long long* __restrict__ key,
                unsigned int* __restrict__ pairs, unsigned int* __restrict__ scans) {
    int n = blockIdx.x * 256 + threadIdx.x;
    float a = 3.4e38f, b2 = 3.4e38f; int ai = -1;
    for (int nb = 0; nb < NB_; ++nb) {
        float n1 = pd1[(size_t)nb * N_ + n];
        int   ni = pi1[(size_t)nb * N_ + n];
        float n2 = pd2[(size_t)nb * N_ + n];
        if (n1 < a) { b2 = fminf(a, n2); a = n1; ai = ni; }
        else        { b2 = fminf(b2, n1); }
    }
    if (b2 - a < MARGIN) {
        const float W = a + MARGIN;
        key[n] = ~0ULL;
        idx[n] = 0x80000000 | ai;          // flagged: resolve from key later
        for (int nb = 0; nb < NB_; ++nb) {
            if (pd2[(size_t)nb * N_ + n] <= W) {
                int q = atomicAdd(&counters[1], 1);
                scans[q] = ((unsigned)n << 5) | (unsigned)nb;
            } else if (pd1[(size_t)nb * N_ + n] <= W) {
                int q = atomicAdd(&counters[0], 1);
                pairs[q] = ((unsigned)n << 13) | (unsigned)pi1[(size_t)nb * N_ + n];
            }
        }
    } else {
        idx[n] = ai;
    }
}

// ---------------- fused exact fp32 recheck (pairs + block scans) ------------
// blocks [0,128): 4 threads per (token, candidate); blocks [128,384): one
// (token, 256-code block) exact scan per task, E rows coalesced.
__global__ __launch_bounds__(256)
void recheck(const float* __restrict__ x, const float* __restrict__ E,
             const float* __restrict__ c, const unsigned int* __restrict__ pairs,
             const unsigned int* __restrict__ scans, const int* __restrict__ counters,
             unsigned long long* __restrict__ key) {
    if (blockIdx.x < 128) {
        int items = counters[0] * 4;
        for (int it = blockIdx.x * 256 + threadIdx.x; it < items; it += 128 * 256) {
            int p = it >> 2, q = it & 3;   // quads stay intact: stride % 4 == 0
            unsigned v = pairs[p];
            int n = v >> 13, k = v & 8191;
            int b = n >> 10, s = n & 1023;
            const float* xb = x + (size_t)b * 262144 + s;
            const float* eb = E + k;
            float acc = 0.f;
            const int d0 = q * 64;
            #pragma unroll 8
            for (int d = d0; d < d0 + 64; ++d)
                acc = fmaf(xb[(size_t)d * HW_], eb[(size_t)d * K_], acc);
            float o1 = __shfl_xor(acc, 1); float s2 = acc + o1;
            float o2 = __shfl_xor(s2, 2);  float tot = s2 + o2;   // ((q0+q1)+(q2+q3))
            if (q == 0) atomicMin(key + n, pack_dk(fmaf(-2.f, tot, c[k]), k));
        }
    } else {
        int cnt = counters[1];
        for (int t = blockIdx.x - 128; t < cnt; t += 256) {
            unsigned v = scans[t];
            int n = v >> 5, nb = v & 31;
            int k = nb * 256 + threadIdx.x;
            int b = n >> 10, s = n & 1023;
            const float* xb = x + (size_t)b * 262144 + s;
            float acc = 0.f;
            #pragma unroll 4
            for (int d = 0; d < D_; ++d)          // ascending d: exact ref chain
                acc = fmaf(xb[(size_t)d * HW_], E[(size_t)d * K_ + k], acc);
            float dist = fmaf(-2.f, acc, c[k]);
            atomicMin(key + n, pack_dk(dist, k));  // (dist,k) lex-min: first-min ties
        }
    }
}

// ---------------- gather + write outputs (float4, fixup via sign bit) -------
__global__ __launch_bounds__(256)
void write_kernel(const float* __restrict__ x, const float* __restrict__ E,
                  const int* __restrict__ idx, const unsigned long long* __restrict__ key,
                  float* __restrict__ out) {
    __shared__ int kst[64];
    const int n0 = blockIdx.x * 64;
    const int b = n0 >> 10, s0 = n0 & 1023;
    const int tid = threadIdx.x;
    if (tid < 64) {
        int v = idx[n0 + tid];
        int k = (v < 0) ? (int)(key[n0 + tid] & 8191ULL) : v;
        kst[tid] = k;
        out[IND_OFF + n0 + tid] = (float)k;
    }
    __syncthreads();
    const int g = tid & 15;               // float4 group of 4 tokens
    const int d0 = tid >> 4;              // 16 d-streams
    const int ka = kst[g * 4], kb2 = kst[g * 4 + 1], kc = kst[g * 4 + 2], kd = kst[g * 4 + 3];
    const float* xb = x + (size_t)b * 262144 + s0 + g * 4;
    float* o0 = out + (size_t)b * 262144 + s0 + g * 4;
    float* o1 = o0 + OUT1_OFF;
    for (int d = d0; d < D_; d += 16) {
        const float* er = E + (size_t)d * K_;
        float4 xv = *(const float4*)(xb + (size_t)d * HW_);
        float4 q;
        q.x = er[ka]; q.y = er[kb2]; q.z = er[kc]; q.w = er[kd];
        float4 r;                          // x + (q - x): replicate jnp fp32 rounding
        r.x = xv.x + (q.x - xv.x); r.y = xv.y + (q.y - xv.y);
        r.z = xv.z + (q.z - xv.z); r.w = xv.w + (q.w - xv.w);
        *(float4*)(o0 + (size_t)d * HW_) = r;
        *(float4*)(o1 + (size_t)d * HW_) = q;
    }
}

extern "C" void kernel_launch(void* const* d_in, const int* in_sizes, int n_in,
                              void* d_out, int out_size, void* d_ws, size_t ws_size,
                              hipStream_t stream) {
    const float* x = (const float*)d_in[0];
    const float* E = (const float*)d_in[1];
    float* out = (float*)d_out;

    char* p = (char*)d_ws;
    ushort* xh = (ushort*)p;                 p += (size_t)N_ * D_ * 2;   // 8 MB
    ushort* xl = (ushort*)p;                 p += (size_t)N_ * D_ * 2;   // 8 MB
    ushort* eh = (ushort*)p;                 p += (size_t)K_ * D_ * 2;   // 4 MB
    float*  c  = (float*)p;                  p += (size_t)K_ * 4;
    float*  pd1 = (float*)p;                 p += (size_t)NB_ * N_ * 4;  // 2 MB
    int*    pi1 = (int*)p;                   p += (size_t)NB_ * N_ * 4;
    float*  pd2 = (float*)p;                 p += (size_t)NB_ * N_ * 4;
    int*    idx = (int*)p;                   p += (size_t)N_ * 4;
    unsigned long long* key = (unsigned long long*)p; p += (size_t)N_ * 8;
    unsigned int* pairs = (unsigned int*)p;  p += (size_t)524288 * 4;    // 2 MB cap
    unsigned int* scans = (unsigned int*)p;  p += (size_t)524288 * 4;    // 2 MB cap
    int*    counters = (int*)p;              p += 256;

    cnorm_kernel<<<K_ / 32, 256, 0, stream>>>(E, c, counters);
    prep_x<<<dim3(32, 8, 16), 256, 0, stream>>>(x, xh, xl);
    prep_e<<<dim3(256, 8), 256, 0, stream>>>(E, eh);
    mfma_kernel<<<8192, 256, 0, stream>>>(xh, xl, eh, c, pd1, pi1, pd2);
    merge_flag<<<N_ / 256, 256, 0, stream>>>(pd1, pi1, pd2, idx, counters, key, pairs, scans);
    recheck<<<384, 256, 0, stream>>>(x, E, c, pairs, scans, counters, key);
    write_kernel<<<N_ / 64, 256, 0, stream>>>(x, E, idx, key, out);
}

// Round 6
// 359.263 us; speedup vs baseline: 1.5195x; 1.1466x over previous
//
#include <hip/hip_runtime.h>
#include <hip/hip_bf16.h>
#include <hip/hip_fp16.h>

// VQ codebook lookup via fp16 MFMA + margin-based candidate recheck.
// x[16,256,32,32] f32, E[256,8192] f32, N=16384 tokens, K=8192 codes.
// R14 (resubmitted R15 — prior bench was an infra container failure, not a
// kernel verdict): replaced split-bf16 (2 MFMA passes) with SINGLE fp16 pass:
//   S = fp16(x)·fp16(e) via mfma_f32_16x16x32_f16; fp16 products are exact
//   in fp32, so dist-err sigma ~7.8e-4 (pairwise-diff ~1.1e-3) — BETTER
//   than the validated split-bf16 scheme (1.54e-3). MARGIN 0.02 is now an
//   ~18-sigma guard (was 13). Halves MFMA work, removes the xl plane and
//   its global loads entirely. Flagged tokens: block top-1s in window ->
//   exact pair recheck; blocks with top-2 in window -> exact 256-code
//   BLOCK scan. Exact path = ascending-d fmaf chain (validated R1-R8).
//   Staging: conflict-free XOR-swizzled global_load_lds (R6/R7-verified).
//   Geometry (R13-verified): block 4 waves, tile 64 tok x 256 codes, wave
//   64x64, 2-phase dbuf, 3 blocks/CU; XCD both-operand L2 residency
//   (R12/R13-verified: FETCH ~25MB): xcd=bid&7 owns mb in [xcd*32,+32).
// Downstream kernels and pd1/pi1/pd2 layout unchanged.

#define D_   256
#define HW_  1024
#define N_   16384
#define K_   8192
#define NB_  32              // 32 code-blocks of 256
#define MARGIN 0.02f         // ~18 sigma of fp16 approx-error difference

#define OUT1_OFF 4194304     // B*D*H*W
#define IND_OFF  8388608

typedef __attribute__((ext_vector_type(8))) _Float16 f16x8;  // 8 f16 = 4 VGPR
typedef __attribute__((ext_vector_type(4))) float f32x4;

__device__ __forceinline__ unsigned long long pack_dk(float dist, int k) {
    unsigned db = __float_as_uint(dist);
    unsigned mono = (db & 0x80000000u) ? ~db : (db | 0x80000000u);
    return ((unsigned long long)mono << 32) | (unsigned)k;
}

// async global->LDS DMA: lane i of the wave lands at ldsbase + 16*i.
__device__ __forceinline__ void async_copy16(const void* g, void* l) {
    __builtin_amdgcn_global_load_lds(
        (const __attribute__((address_space(1))) void*)g,
        (__attribute__((address_space(3))) void*)l, 16, 0, 0);
}

// ---------------- codebook column norms + counter zeroing -------------------
__global__ __launch_bounds__(256)
void cnorm_kernel(const float* __restrict__ E, float* __restrict__ c,
                  int* __restrict__ counters) {
    if (blockIdx.x == 0 && threadIdx.x < 2) counters[threadIdx.x] = 0;
    __shared__ float part[8][32];
    const int tid = threadIdx.x;
    const int cl = tid & 31, q = tid >> 5;
    const int k = blockIdx.x * 32 + cl;
    float s = 0.f;
    #pragma unroll 8
    for (int d = q * 32; d < q * 32 + 32; ++d) {
        float v = E[(size_t)d * K_ + k];
        s = fmaf(v, v, s);
    }
    part[q][cl] = s;
    __syncthreads();
    if (tid < 32) {   // fixed combine order: deterministic
        float t0 = (part[0][tid] + part[1][tid]) + (part[2][tid] + part[3][tid]);
        float t1 = (part[4][tid] + part[5][tid]) + (part[6][tid] + part[7][tid]);
        c[blockIdx.x * 32 + tid] = t0 + t1;
    }
}

// ---------------- prep: x fp32 -> fp16 plane, transposed to token-major -----
__global__ __launch_bounds__(256)
void prep_x(const float* __restrict__ x, ushort* __restrict__ xf) {
    __shared__ float t[32][33];
    const int s0 = blockIdx.x * 32, d0 = blockIdx.y * 32, b = blockIdx.z;
    const int tid = threadIdx.x;
    #pragma unroll
    for (int j = 0; j < 4; ++j) {
        int i = tid + 256 * j; int dd = i >> 5, ss = i & 31;
        t[dd][ss] = x[(size_t)b * 262144 + (size_t)(d0 + dd) * 1024 + s0 + ss];
    }
    __syncthreads();
    #pragma unroll
    for (int j = 0; j < 4; ++j) {
        int i = tid + 256 * j; int ss = i >> 5, dd = i & 31;
        _Float16 h = (_Float16)t[dd][ss];          // RN f32->f16
        size_t o = (size_t)(b * 1024 + s0 + ss) * D_ + d0 + dd;
        xf[o] = *(ushort*)&h;
    }
}

// E[d][k] -> ef[k][d] fp16
__global__ __launch_bounds__(256)
void prep_e(const float* __restrict__ E, ushort* __restrict__ ef) {
    __shared__ float t[32][33];
    const int k0 = blockIdx.x * 32, d0 = blockIdx.y * 32;
    const int tid = threadIdx.x;
    #pragma unroll
    for (int j = 0; j < 4; ++j) {
        int i = tid + 256 * j; int dd = i >> 5, kk = i & 31;
        t[dd][kk] = E[(size_t)(d0 + dd) * K_ + k0 + kk];
    }
    __syncthreads();
    #pragma unroll
    for (int j = 0; j < 4; ++j) {
        int i = tid + 256 * j; int kk = i >> 5, dd = i & 31;
        _Float16 h = (_Float16)t[dd][kk];
        ef[(size_t)(k0 + kk) * D_ + d0 + dd] = *(ushort*)&h;
    }
}

// ---------------- MFMA distance + per-token top-2 per 256-code block --------
// grid 8192 flat, XCD-partitioned. block 256 = 4 waves, block tile 64 tokens
// x 256 codes, wave tile 64x64 (acc[4][4]). 2-phase dbuf, prefetch t+1
// before compute of t, one __syncthreads per step. LDS rows = 64B of 4x16B
// chunks, chunk position = chunk ^ ((row>>1)&3) — conflict-free (verified).
__global__ __launch_bounds__(256, 3)
void mfma_kernel(const ushort* __restrict__ xf,
                 const ushort* __restrict__ ef,
                 const float* __restrict__ c,
                 float* __restrict__ pd1, int* __restrict__ pi1, float* __restrict__ pd2) {
    __shared__ __align__(16) ushort Ah[2][2048];   // [2][64*32]  8 KB
    __shared__ __align__(16) ushort Bb[2][8192];   // [2][256*32] 32 KB
    __shared__ float redm1[320], redm2[320];       // [64][5] padded
    __shared__ int   redi1[320];

    const int tid = threadIdx.x;
    // XCD partition: xcd owns mb in [xcd*32, xcd*32+32); nb slow within xcd.
    const int bid = blockIdx.x;
    const int xcd = bid & 7, rr = bid >> 3;
    const int nb = rr >> 5, mb = xcd * 32 + (rr & 31);
    const int n0 = mb * 64, k0 = nb * 256;
    const int lane = tid & 63, w = tid >> 6;       // w = code quadrant 0..3
    const int l15 = lane & 15, lq = lane >> 4;

    // A staging: 1 gload_lds per wave per step (4 waves cover 64 rows)
    size_t aoff;
    {
        int slot = w * 64 + lane;
        int t = slot >> 2, cp = slot & 3;
        int cs = cp ^ ((t >> 1) & 3);
        aoff = (size_t)(n0 + t) * D_ + cs * 8;
    }
    const int adst = w * 512;                      // ushort offset
    // B staging: 4 gload_lds per wave per step
    size_t boff[4]; int bdst[4];
    #pragma unroll
    for (int g = 0; g < 4; ++g) {
        int slot = (w * 4 + g) * 64 + lane;
        int t = slot >> 2, cp = slot & 3;
        int cs = cp ^ ((t >> 1) & 3);
        boff[g] = (size_t)(k0 + t) * D_ + cs * 8;
        bdst[g] = (w * 4 + g) * 512;
    }
    // fragment read offsets (XOR matches staging swizzle)
    int aro[4], bro[4];
    #pragma unroll
    for (int mt = 0; mt < 4; ++mt) {
        int R = mt * 16 + l15;
        aro[mt] = R * 32 + ((lq ^ ((R >> 1) & 3)) * 8);
    }
    #pragma unroll
    for (int nt = 0; nt < 4; ++nt) {
        int R = w * 64 + nt * 16 + l15;
        bro[nt] = R * 32 + ((lq ^ ((R >> 1) & 3)) * 8);
    }

    f32x4 acc[4][4];
    #pragma unroll
    for (int mt = 0; mt < 4; ++mt)
        #pragma unroll
        for (int nt = 0; nt < 4; ++nt) acc[mt][nt] = (f32x4){0.f, 0.f, 0.f, 0.f};

    // prologue: stage step 0 into buffer 0
    async_copy16(xf + aoff, &Ah[0][adst]);
    #pragma unroll
    for (int g = 0; g < 4; ++g)
        async_copy16(ef + boff[g], &Bb[0][bdst[g]]);
    __syncthreads();

    #pragma unroll
    for (int db = 0; db < 8; ++db) {
        const int cur = db & 1;
        const int d0 = db * 32;
        if (db < 7) {   // prefetch step t+1 into the other buffer
            const int dn = d0 + 32;
            async_copy16(xf + aoff + dn, &Ah[cur ^ 1][adst]);
            #pragma unroll
            for (int g = 0; g < 4; ++g)
                async_copy16(ef + boff[g] + dn, &Bb[cur ^ 1][bdst[g]]);
        }
        f16x8 a[4], b[4];
        #pragma unroll
        for (int mt = 0; mt < 4; ++mt)
            a[mt] = *(const f16x8*)&Ah[cur][aro[mt]];
        #pragma unroll
        for (int nt = 0; nt < 4; ++nt)
            b[nt] = *(const f16x8*)&Bb[cur][bro[nt]];
        #pragma unroll
        for (int nt = 0; nt < 4; ++nt)
            #pragma unroll
            for (int mt = 0; mt < 4; ++mt)
                acc[mt][nt] = __builtin_amdgcn_mfma_f32_16x16x32_f16(a[mt], b[nt], acc[mt][nt], 0, 0, 0);
        __syncthreads();   // drains prefetch; protects buffer reuse
    }

    float cv[4];
    #pragma unroll
    for (int nt = 0; nt < 4; ++nt) cv[nt] = c[k0 + w * 64 + nt * 16 + l15];

    float m1[16], m2[16]; int i1[16];
    #pragma unroll
    for (int mt = 0; mt < 4; ++mt)
        #pragma unroll
        for (int r = 0; r < 4; ++r) {
            int p = mt * 4 + r;
            float a = 3.4e38f, b2 = 3.4e38f; int ai = -1;
            #pragma unroll
            for (int nt = 0; nt < 4; ++nt) {
                float d = fmaf(-2.f, acc[mt][nt][r], cv[nt]);
                int k = k0 + w * 64 + nt * 16 + l15;
                if (d < a) { b2 = a; a = d; ai = k; } else if (d < b2) b2 = d;
            }
            m1[p] = a; i1[p] = ai; m2[p] = b2;
        }
    #pragma unroll
    for (int s = 1; s < 16; s <<= 1) {
        #pragma unroll
        for (int p = 0; p < 16; ++p) {
            float n1 = __shfl_xor(m1[p], s);
            int   ni = __shfl_xor(i1[p], s);
            float n2 = __shfl_xor(m2[p], s);
            if (n1 < m1[p]) { m2[p] = fminf(m1[p], n2); m1[p] = n1; i1[p] = ni; }
            else            { m2[p] = fminf(m2[p], n1); }
        }
    }
    if (l15 == 0) {
        #pragma unroll
        for (int mt = 0; mt < 4; ++mt)
            #pragma unroll
            for (int r = 0; r < 4; ++r) {
                int p = mt * 4 + r;
                int t = mt * 16 + lq * 4 + r;
                redm1[t * 5 + w] = m1[p]; redi1[t * 5 + w] = i1[p]; redm2[t * 5 + w] = m2[p];
            }
    }
    __syncthreads();
    if (tid < 64) {   // fixed combine order w=0..3: deterministic
        float a = redm1[tid * 5], b2 = redm2[tid * 5]; int ai = redi1[tid * 5];
        #pragma unroll
        for (int q = 1; q < 4; ++q) {
            float n1 = redm1[tid * 5 + q], n2 = redm2[tid * 5 + q]; int ni = redi1[tid * 5 + q];
            if (n1 < a) { b2 = fminf(a, n2); a = n1; ai = ni; }
            else        { b2 = fminf(b2, n1); }
        }
        size_t o = (size_t)nb * N_ + n0 + tid;
        pd1[o] = a; pi1[o] = ai; pd2[o] = b2;
    }
}

// ---------------- merge 32 blocks; enumerate pair/scan candidates -----------
// counters[0]=pairs, [1]=block-scan tasks. Coverage: true winner j in block B
// is B's top-1 (pd1<=W -> pair) or has obs >= pd2_B, forcing pd2_B<=W -> B
// gets an exact 256-code scan which covers ANY rank in B.
__global__ __launch_bounds__(256)
void merge_flag(const float* __restrict__ pd1, const int* __restrict__ pi1,
                const float* __restrict__ pd2,
                int* __restrict__ idx, int* __restrict__ counters,
                unsigned long long* __restrict__ key,
                unsigned int* __restrict__ pairs, unsigned int* __restrict__ scans) {
    int n = blockIdx.x * 256 + threadIdx.x;
    float a = 3.4e38f, b2 = 3.4e38f; int ai = -1;
    for (int nb = 0; nb < NB_; ++nb) {
        float n1 = pd1[(size_t)nb * N_ + n];
        int   ni = pi1[(size_t)nb * N_ + n];
        float n2 = pd2[(size_t)nb * N_ + n];
        if (n1 < a) { b2 = fminf(a, n2); a = n1; ai = ni; }
        else        { b2 = fminf(b2, n1); }
    }
    if (b2 - a < MARGIN) {
        const float W = a + MARGIN;
        key[n] = ~0ULL;
        idx[n] = 0x80000000 | ai;          // flagged: resolve from key later
        for (int nb = 0; nb < NB_; ++nb) {
            if (pd2[(size_t)nb * N_ + n] <= W) {
                int q = atomicAdd(&counters[1], 1);
                scans[q] = ((unsigned)n << 5) | (unsigned)nb;
            } else if (pd1[(size_t)nb * N_ + n] <= W) {
                int q = atomicAdd(&counters[0], 1);
                pairs[q] = ((unsigned)n << 13) | (unsigned)pi1[(size_t)nb * N_ + n];
            }
        }
    } else {
        idx[n] = ai;
    }
}

// ---------------- fused exact fp32 recheck (pairs + block scans) ------------
// blocks [0,128): 4 threads per (token, candidate); blocks [128,384): one
// (token, 256-code block) exact scan per task, E rows coalesced.
__global__ __launch_bounds__(256)
void recheck(const float* __restrict__ x, const float* __restrict__ E,
             const float* __restrict__ c, const unsigned int* __restrict__ pairs,
             const unsigned int* __restrict__ scans, const int* __restrict__ counters,
             unsigned long long* __restrict__ key) {
    if (blockIdx.x < 128) {
        int items = counters[0] * 4;
        for (int it = blockIdx.x * 256 + threadIdx.x; it < items; it += 128 * 256) {
            int p = it >> 2, q = it & 3;   // quads stay intact: stride % 4 == 0
            unsigned v = pairs[p];
            int n = v >> 13, k = v & 8191;
            int b = n >> 10, s = n & 1023;
            const float* xb = x + (size_t)b * 262144 + s;
            const float* eb = E + k;
            float acc = 0.f;
            const int d0 = q * 64;
            #pragma unroll 8
            for (int d = d0; d < d0 + 64; ++d)
                acc = fmaf(xb[(size_t)d * HW_], eb[(size_t)d * K_], acc);
            float o1 = __shfl_xor(acc, 1); float s2 = acc + o1;
            float o2 = __shfl_xor(s2, 2);  float tot = s2 + o2;   // ((q0+q1)+(q2+q3))
            if (q == 0) atomicMin(key + n, pack_dk(fmaf(-2.f, tot, c[k]), k));
        }
    } else {
        int cnt = counters[1];
        for (int t = blockIdx.x - 128; t < cnt; t += 256) {
            unsigned v = scans[t];
            int n = v >> 5, nb = v & 31;
            int k = nb * 256 + threadIdx.x;
            int b = n >> 10, s = n & 1023;
            const float* xb = x + (size_t)b * 262144 + s;
            float acc = 0.f;
            #pragma unroll 4
            for (int d = 0; d < D_; ++d)          // ascending d: exact ref chain
                acc = fmaf(xb[(size_t)d * HW_], E[(size_t)d * K_ + k], acc);
            float dist = fmaf(-2.f, acc, c[k]);
            atomicMin(key + n, pack_dk(dist, k));  // (dist,k) lex-min: first-min ties
        }
    }
}

// ---------------- gather + write outputs (float4, fixup via sign bit) -------
__global__ __launch_bounds__(256)
void write_kernel(const float* __restrict__ x, const float* __restrict__ E,
                  const int* __restrict__ idx, const unsigned long long* __restrict__ key,
                  float* __restrict__ out) {
    __shared__ int kst[64];
    const int n0 = blockIdx.x * 64;
    const int b = n0 >> 10, s0 = n0 & 1023;
    const int tid = threadIdx.x;
    if (tid < 64) {
        int v = idx[n0 + tid];
        int k = (v < 0) ? (int)(key[n0 + tid] & 8191ULL) : v;
        kst[tid] = k;
        out[IND_OFF + n0 + tid] = (float)k;
    }
    __syncthreads();
    const int g = tid & 15;               // float4 group of 4 tokens
    const int d0 = tid >> 4;              // 16 d-streams
    const int ka = kst[g * 4], kb2 = kst[g * 4 + 1], kc = kst[g * 4 + 2], kd = kst[g * 4 + 3];
    const float* xb = x + (size_t)b * 262144 + s0 + g * 4;
    float* o0 = out + (size_t)b * 262144 + s0 + g * 4;
    float* o1 = o0 + OUT1_OFF;
    for (int d = d0; d < D_; d += 16) {
        const float* er = E + (size_t)d * K_;
        float4 xv = *(const float4*)(xb + (size_t)d * HW_);
        float4 q;
        q.x = er[ka]; q.y = er[kb2]; q.z = er[kc]; q.w = er[kd];
        float4 r;                          // x + (q - x): replicate jnp fp32 rounding
        r.x = xv.x + (q.x - xv.x); r.y = xv.y + (q.y - xv.y);
        r.z = xv.z + (q.z - xv.z); r.w = xv.w + (q.w - xv.w);
        *(float4*)(o0 + (size_t)d * HW_) = r;
        *(float4*)(o1 + (size_t)d * HW_) = q;
    }
}

extern "C" void kernel_launch(void* const* d_in, const int* in_sizes, int n_in,
                              void* d_out, int out_size, void* d_ws, size_t ws_size,
                              hipStream_t stream) {
    const float* x = (const float*)d_in[0];
    const float* E = (const float*)d_in[1];
    float* out = (float*)d_out;

    char* p = (char*)d_ws;
    ushort* xf = (ushort*)p;                 p += (size_t)N_ * D_ * 2;   // 8 MB
    ushort* ef = (ushort*)p;                 p += (size_t)K_ * D_ * 2;   // 4 MB
    float*  c  = (float*)p;                  p += (size_t)K_ * 4;
    float*  pd1 = (float*)p;                 p += (size_t)NB_ * N_ * 4;  // 2 MB
    int*    pi1 = (int*)p;                   p += (size_t)NB_ * N_ * 4;
    float*  pd2 = (float*)p;                 p += (size_t)NB_ * N_ * 4;
    int*    idx = (int*)p;                   p += (size_t)N_ * 4;
    unsigned long long* key = (unsigned long long*)p; p += (size_t)N_ * 8;
    unsigned int* pairs = (unsigned int*)p;  p += (size_t)524288 * 4;    // 2 MB cap
    unsigned int* scans = (unsigned int*)p;  p += (size_t)524288 * 4;    // 2 MB cap
    int*    counters = (int*)p;              p += 256;

    cnorm_kernel<<<K_ / 32, 256, 0, stream>>>(E, c, counters);
    prep_x<<<dim3(32, 8, 16), 256, 0, stream>>>(x, xf);
    prep_e<<<dim3(256, 8), 256, 0, stream>>>(E, ef);
    mfma_kernel<<<8192, 256, 0, stream>>>(xf, ef, c, pd1, pi1, pd2);
    merge_flag<<<N_ / 256, 256, 0, stream>>>(pd1, pi1, pd2, idx, counters, key, pairs, scans);
    recheck<<<384, 256, 0, stream>>>(x, E, c, pairs, scans, counters, key);
    write_kernel<<<N_ / 64, 256, 0, stream>>>(x, E, idx, key, out);
}

// Round 7
// 353.753 us; speedup vs baseline: 1.5431x; 1.0156x over previous
//
#include <hip/hip_runtime.h>
#include <hip/hip_bf16.h>
#include <hip/hip_fp16.h>

// VQ codebook lookup via fp16 MFMA + margin-based candidate recheck.
// x[16,256,32,32] f32, E[256,8192] f32, N=16384 tokens, K=8192 codes.
// S = fp16(x)·fp16(e) via mfma_f32_16x16x32_f16 (fp16 products exact in
// fp32): dist-err sigma ~7.8e-4, pairwise ~1.1e-3; MARGIN 0.02 ~ 18 sigma.
// Flagged tokens: block top-1s in window -> exact pair recheck; blocks with
// top-2 in window -> exact 256-code BLOCK scan. Exact path = ascending-d
// fmaf chain (validated R1-R8). Staging: conflict-free XOR-swizzled
// global_load_lds (R6/R7-verified). Geometry (R13/R14-verified, 180.5us):
// block 4 waves, tile 64 tok x 256 codes, wave 64x64, 3 blocks/CU; XCD
// both-operand L2 residency (FETCH ~21MB): xcd=bid&7 owns mb [xcd*32,+32).
//
// R16: loop sync only — __syncthreads-per-step (which drains vmcnt(0),
//   exposing load latency every step; the ~150us fixed stall seen across
//   R10/R13/R14) replaced by depth-2 prefetch + counted vmcnt + raw
//   s_barrier (m201-pattern): prologue issues S0+S1 (10 loads/wave);
//   step t: vmcnt(5) [oldest 5 = S_t retired; in-order], barrier,
//   compute, barrier, issue S_{t+2} into the vacated buffer. No barrier
//   drains in-flight prefetch; each load gets a full step of cover.
// Downstream kernels and pd1/pi1/pd2 layout unchanged.

#define D_   256
#define HW_  1024
#define N_   16384
#define K_   8192
#define NB_  32              // 32 code-blocks of 256
#define MARGIN 0.02f         // ~18 sigma of fp16 approx-error difference

#define OUT1_OFF 4194304     // B*D*H*W
#define IND_OFF  8388608

typedef __attribute__((ext_vector_type(8))) _Float16 f16x8;  // 8 f16 = 4 VGPR
typedef __attribute__((ext_vector_type(4))) float f32x4;

__device__ __forceinline__ unsigned long long pack_dk(float dist, int k) {
    unsigned db = __float_as_uint(dist);
    unsigned mono = (db & 0x80000000u) ? ~db : (db | 0x80000000u);
    return ((unsigned long long)mono << 32) | (unsigned)k;
}

// async global->LDS DMA: lane i of the wave lands at ldsbase + 16*i.
__device__ __forceinline__ void async_copy16(const void* g, void* l) {
    __builtin_amdgcn_global_load_lds(
        (const __attribute__((address_space(1))) void*)g,
        (__attribute__((address_space(3))) void*)l, 16, 0, 0);
}

// ---------------- codebook column norms + counter zeroing -------------------
__global__ __launch_bounds__(256)
void cnorm_kernel(const float* __restrict__ E, float* __restrict__ c,
                  int* __restrict__ counters) {
    if (blockIdx.x == 0 && threadIdx.x < 2) counters[threadIdx.x] = 0;
    __shared__ float part[8][32];
    const int tid = threadIdx.x;
    const int cl = tid & 31, q = tid >> 5;
    const int k = blockIdx.x * 32 + cl;
    float s = 0.f;
    #pragma unroll 8
    for (int d = q * 32; d < q * 32 + 32; ++d) {
        float v = E[(size_t)d * K_ + k];
        s = fmaf(v, v, s);
    }
    part[q][cl] = s;
    __syncthreads();
    if (tid < 32) {   // fixed combine order: deterministic
        float t0 = (part[0][tid] + part[1][tid]) + (part[2][tid] + part[3][tid]);
        float t1 = (part[4][tid] + part[5][tid]) + (part[6][tid] + part[7][tid]);
        c[blockIdx.x * 32 + tid] = t0 + t1;
    }
}

// ---------------- prep: x fp32 -> fp16 plane, transposed to token-major -----
__global__ __launch_bounds__(256)
void prep_x(const float* __restrict__ x, ushort* __restrict__ xf) {
    __shared__ float t[32][33];
    const int s0 = blockIdx.x * 32, d0 = blockIdx.y * 32, b = blockIdx.z;
    const int tid = threadIdx.x;
    #pragma unroll
    for (int j = 0; j < 4; ++j) {
        int i = tid + 256 * j; int dd = i >> 5, ss = i & 31;
        t[dd][ss] = x[(size_t)b * 262144 + (size_t)(d0 + dd) * 1024 + s0 + ss];
    }
    __syncthreads();
    #pragma unroll
    for (int j = 0; j < 4; ++j) {
        int i = tid + 256 * j; int ss = i >> 5, dd = i & 31;
        _Float16 h = (_Float16)t[dd][ss];          // RN f32->f16
        size_t o = (size_t)(b * 1024 + s0 + ss) * D_ + d0 + dd;
        xf[o] = *(ushort*)&h;
    }
}

// E[d][k] -> ef[k][d] fp16
__global__ __launch_bounds__(256)
void prep_e(const float* __restrict__ E, ushort* __restrict__ ef) {
    __shared__ float t[32][33];
    const int k0 = blockIdx.x * 32, d0 = blockIdx.y * 32;
    const int tid = threadIdx.x;
    #pragma unroll
    for (int j = 0; j < 4; ++j) {
        int i = tid + 256 * j; int dd = i >> 5, kk = i & 31;
        t[dd][kk] = E[(size_t)(d0 + dd) * K_ + k0 + kk];
    }
    __syncthreads();
    #pragma unroll
    for (int j = 0; j < 4; ++j) {
        int i = tid + 256 * j; int kk = i >> 5, dd = i & 31;
        _Float16 h = (_Float16)t[dd][kk];
        ef[(size_t)(k0 + kk) * D_ + d0 + dd] = *(ushort*)&h;
    }
}

// ---------------- MFMA distance + per-token top-2 per 256-code block --------
// grid 8192 flat, XCD-partitioned. block 256 = 4 waves, block tile 64 tokens
// x 256 codes, wave tile 64x64 (acc[4][4]). Depth-2 prefetch, counted
// vmcnt(5), raw s_barrier (no drains in loop). LDS rows = 64B of 4x16B
// chunks, chunk position = chunk ^ ((row>>1)&3) — conflict-free (verified).
__global__ __launch_bounds__(256, 3)
void mfma_kernel(const ushort* __restrict__ xf,
                 const ushort* __restrict__ ef,
                 const float* __restrict__ c,
                 float* __restrict__ pd1, int* __restrict__ pi1, float* __restrict__ pd2) {
    __shared__ __align__(16) ushort Ah[2][2048];   // [2][64*32]  8 KB
    __shared__ __align__(16) ushort Bb[2][8192];   // [2][256*32] 32 KB
    __shared__ float redm1[320], redm2[320];       // [64][5] padded
    __shared__ int   redi1[320];

    const int tid = threadIdx.x;
    // XCD partition: xcd owns mb in [xcd*32, xcd*32+32); nb slow within xcd.
    const int bid = blockIdx.x;
    const int xcd = bid & 7, rr = bid >> 3;
    const int nb = rr >> 5, mb = xcd * 32 + (rr & 31);
    const int n0 = mb * 64, k0 = nb * 256;
    const int lane = tid & 63, w = tid >> 6;       // w = code quadrant 0..3
    const int l15 = lane & 15, lq = lane >> 4;

    // A staging: 1 gload_lds per wave per step (4 waves cover 64 rows)
    size_t aoff;
    {
        int slot = w * 64 + lane;
        int t = slot >> 2, cp = slot & 3;
        int cs = cp ^ ((t >> 1) & 3);
        aoff = (size_t)(n0 + t) * D_ + cs * 8;
    }
    const int adst = w * 512;                      // ushort offset
    // B staging: 4 gload_lds per wave per step
    size_t boff[4]; int bdst[4];
    #pragma unroll
    for (int g = 0; g < 4; ++g) {
        int slot = (w * 4 + g) * 64 + lane;
        int t = slot >> 2, cp = slot & 3;
        int cs = cp ^ ((t >> 1) & 3);
        boff[g] = (size_t)(k0 + t) * D_ + cs * 8;
        bdst[g] = (w * 4 + g) * 512;
    }
    // fragment read offsets (XOR matches staging swizzle)
    int aro[4], bro[4];
    #pragma unroll
    for (int mt = 0; mt < 4; ++mt) {
        int R = mt * 16 + l15;
        aro[mt] = R * 32 + ((lq ^ ((R >> 1) & 3)) * 8);
    }
    #pragma unroll
    for (int nt = 0; nt < 4; ++nt) {
        int R = w * 64 + nt * 16 + l15;
        bro[nt] = R * 32 + ((lq ^ ((R >> 1) & 3)) * 8);
    }

    f32x4 acc[4][4];
    #pragma unroll
    for (int mt = 0; mt < 4; ++mt)
        #pragma unroll
        for (int nt = 0; nt < 4; ++nt) acc[mt][nt] = (f32x4){0.f, 0.f, 0.f, 0.f};

    // prologue: depth-2 prefetch — stage steps 0 and 1 (10 loads/wave).
    async_copy16(xf + aoff, &Ah[0][adst]);
    #pragma unroll
    for (int g = 0; g < 4; ++g)
        async_copy16(ef + boff[g], &Bb[0][bdst[g]]);
    async_copy16(xf + aoff + 32, &Ah[1][adst]);
    #pragma unroll
    for (int g = 0; g < 4; ++g)
        async_copy16(ef + boff[g] + 32, &Bb[1][bdst[g]]);

    #pragma unroll
    for (int db = 0; db < 8; ++db) {
        const int cur = db & 1;
        // wait S_db only: vmcnt retires oldest-first; 5 newer stay in flight.
        if (db < 7) asm volatile("s_waitcnt vmcnt(5)" ::: "memory");
        else        asm volatile("s_waitcnt vmcnt(0)" ::: "memory");
        __builtin_amdgcn_s_barrier();   // all waves' S_db loads complete
        f16x8 a[4], b[4];
        #pragma unroll
        for (int mt = 0; mt < 4; ++mt)
            a[mt] = *(const f16x8*)&Ah[cur][aro[mt]];
        #pragma unroll
        for (int nt = 0; nt < 4; ++nt)
            b[nt] = *(const f16x8*)&Bb[cur][bro[nt]];
        #pragma unroll
        for (int nt = 0; nt < 4; ++nt)
            #pragma unroll
            for (int mt = 0; mt < 4; ++mt)
                acc[mt][nt] = __builtin_amdgcn_mfma_f32_16x16x32_f16(a[mt], b[nt], acc[mt][nt], 0, 0, 0);
        __builtin_amdgcn_s_barrier();   // all waves done READING buf[cur]
        if (db < 6) {                   // issue S_{db+2} into vacated buf[cur]
            const int dn = (db + 2) * 32;
            async_copy16(xf + aoff + dn, &Ah[cur][adst]);
            #pragma unroll
            for (int g = 0; g < 4; ++g)
                async_copy16(ef + boff[g] + dn, &Bb[cur][bdst[g]]);
        }
    }

    float cv[4];
    #pragma unroll
    for (int nt = 0; nt < 4; ++nt) cv[nt] = c[k0 + w * 64 + nt * 16 + l15];

    float m1[16], m2[16]; int i1[16];
    #pragma unroll
    for (int mt = 0; mt < 4; ++mt)
        #pragma unroll
        for (int r = 0; r < 4; ++r) {
            int p = mt * 4 + r;
            float a = 3.4e38f, b2 = 3.4e38f; int ai = -1;
            #pragma unroll
            for (int nt = 0; nt < 4; ++nt) {
                float d = fmaf(-2.f, acc[mt][nt][r], cv[nt]);
                int k = k0 + w * 64 + nt * 16 + l15;
                if (d < a) { b2 = a; a = d; ai = k; } else if (d < b2) b2 = d;
            }
            m1[p] = a; i1[p] = ai; m2[p] = b2;
        }
    #pragma unroll
    for (int s = 1; s < 16; s <<= 1) {
        #pragma unroll
        for (int p = 0; p < 16; ++p) {
            float n1 = __shfl_xor(m1[p], s);
            int   ni = __shfl_xor(i1[p], s);
            float n2 = __shfl_xor(m2[p], s);
            if (n1 < m1[p]) { m2[p] = fminf(m1[p], n2); m1[p] = n1; i1[p] = ni; }
            else            { m2[p] = fminf(m2[p], n1); }
        }
    }
    if (l15 == 0) {
        #pragma unroll
        for (int mt = 0; mt < 4; ++mt)
            #pragma unroll
            for (int r = 0; r < 4; ++r) {
                int p = mt * 4 + r;
                int t = mt * 16 + lq * 4 + r;
                redm1[t * 5 + w] = m1[p]; redi1[t * 5 + w] = i1[p]; redm2[t * 5 + w] = m2[p];
            }
    }
    __syncthreads();
    if (tid < 64) {   // fixed combine order w=0..3: deterministic
        float a = redm1[tid * 5], b2 = redm2[tid * 5]; int ai = redi1[tid * 5];
        #pragma unroll
        for (int q = 1; q < 4; ++q) {
            float n1 = redm1[tid * 5 + q], n2 = redm2[tid * 5 + q]; int ni = redi1[tid * 5 + q];
            if (n1 < a) { b2 = fminf(a, n2); a = n1; ai = ni; }
            else        { b2 = fminf(b2, n1); }
        }
        size_t o = (size_t)nb * N_ + n0 + tid;
        pd1[o] = a; pi1[o] = ai; pd2[o] = b2;
    }
}

// ---------------- merge 32 blocks; enumerate pair/scan candidates -----------
// counters[0]=pairs, [1]=block-scan tasks. Coverage: true winner j in block B
// is B's top-1 (pd1<=W -> pair) or has obs >= pd2_B, forcing pd2_B<=W -> B
// gets an exact 256-code scan which covers ANY rank in B.
__global__ __launch_bounds__(256)
void merge_flag(const float* __restrict__ pd1, const int* __restrict__ pi1,
                const float* __restrict__ pd2,
                int* __restrict__ idx, int* __restrict__ counters,
                unsigned long long* __restrict__ key,
                unsigned int* __restrict__ pairs, unsigned int* __restrict__ scans) {
    int n = blockIdx.x * 256 + threadIdx.x;
    float a = 3.4e38f, b2 = 3.4e38f; int ai = -1;
    for (int nb = 0; nb < NB_; ++nb) {
        float n1 = pd1[(size_t)nb * N_ + n];
        int   ni = pi1[(size_t)nb * N_ + n];
        float n2 = pd2[(size_t)nb * N_ + n];
        if (n1 < a) { b2 = fminf(a, n2); a = n1; ai = ni; }
        else        { b2 = fminf(b2, n1); }
    }
    if (b2 - a < MARGIN) {
        const float W = a + MARGIN;
        key[n] = ~0ULL;
        idx[n] = 0x80000000 | ai;          // flagged: resolve from key later
        for (int nb = 0; nb < NB_; ++nb) {
            if (pd2[(size_t)nb * N_ + n] <= W) {
                int q = atomicAdd(&counters[1], 1);
                scans[q] = ((unsigned)n << 5) | (unsigned)nb;
            } else if (pd1[(size_t)nb * N_ + n] <= W) {
                int q = atomicAdd(&counters[0], 1);
                pairs[q] = ((unsigned)n << 13) | (unsigned)pi1[(size_t)nb * N_ + n];
            }
        }
    } else {
        idx[n] = ai;
    }
}

// ---------------- fused exact fp32 recheck (pairs + block scans) ------------
// blocks [0,128): 4 threads per (token, candidate); blocks [128,384): one
// (token, 256-code block) exact scan per task, E rows coalesced.
__global__ __launch_bounds__(256)
void recheck(const float* __restrict__ x, const float* __restrict__ E,
             const float* __restrict__ c, const unsigned int* __restrict__ pairs,
             const unsigned int* __restrict__ scans, const int* __restrict__ counters,
             unsigned long long* __restrict__ key) {
    if (blockIdx.x < 128) {
        int items = counters[0] * 4;
        for (int it = blockIdx.x * 256 + threadIdx.x; it < items; it += 128 * 256) {
            int p = it >> 2, q = it & 3;   // quads stay intact: stride % 4 == 0
            unsigned v = pairs[p];
            int n = v >> 13, k = v & 8191;
            int b = n >> 10, s = n & 1023;
            const float* xb = x + (size_t)b * 262144 + s;
            const float* eb = E + k;
            float acc = 0.f;
            const int d0 = q * 64;
            #pragma unroll 8
            for (int d = d0; d < d0 + 64; ++d)
                acc = fmaf(xb[(size_t)d * HW_], eb[(size_t)d * K_], acc);
            float o1 = __shfl_xor(acc, 1); float s2 = acc + o1;
            float o2 = __shfl_xor(s2, 2);  float tot = s2 + o2;   // ((q0+q1)+(q2+q3))
            if (q == 0) atomicMin(key + n, pack_dk(fmaf(-2.f, tot, c[k]), k));
        }
    } else {
        int cnt = counters[1];
        for (int t = blockIdx.x - 128; t < cnt; t += 256) {
            unsigned v = scans[t];
            int n = v >> 5, nb = v & 31;
            int k = nb * 256 + threadIdx.x;
            int b = n >> 10, s = n & 1023;
            const float* xb = x + (size_t)b * 262144 + s;
            float acc = 0.f;
            #pragma unroll 4
            for (int d = 0; d < D_; ++d)          // ascending d: exact ref chain
                acc = fmaf(xb[(size_t)d * HW_], E[(size_t)d * K_ + k], acc);
            float dist = fmaf(-2.f, acc, c[k]);
            atomicMin(key + n, pack_dk(dist, k));  // (dist,k) lex-min: first-min ties
        }
    }
}

// ---------------- gather + write outputs (float4, fixup via sign bit) -------
__global__ __launch_bounds__(256)
void write_kernel(const float* __restrict__ x, const float* __restrict__ E,
                  const int* __restrict__ idx, const unsigned long long* __restrict__ key,
                  float* __restrict__ out) {
    __shared__ int kst[64];
    const int n0 = blockIdx.x * 64;
    const int b = n0 >> 10, s0 = n0 & 1023;
    const int tid = threadIdx.x;
    if (tid < 64) {
        int v = idx[n0 + tid];
        int k = (v < 0) ? (int)(key[n0 + tid] & 8191ULL) : v;
        kst[tid] = k;
        out[IND_OFF + n0 + tid] = (float)k;
    }
    __syncthreads();
    const int g = tid & 15;               // float4 group of 4 tokens
    const int d0 = tid >> 4;              // 16 d-streams
    const int ka = kst[g * 4], kb2 = kst[g * 4 + 1], kc = kst[g * 4 + 2], kd = kst[g * 4 + 3];
    const float* xb = x + (size_t)b * 262144 + s0 + g * 4;
    float* o0 = out + (size_t)b * 262144 + s0 + g * 4;
    float* o1 = o0 + OUT1_OFF;
    for (int d = d0; d < D_; d += 16) {
        const float* er = E + (size_t)d * K_;
        float4 xv = *(const float4*)(xb + (size_t)d * HW_);
        float4 q;
        q.x = er[ka]; q.y = er[kb2]; q.z = er[kc]; q.w = er[kd];
        float4 r;                          // x + (q - x): replicate jnp fp32 rounding
        r.x = xv.x + (q.x - xv.x); r.y = xv.y + (q.y - xv.y);
        r.z = xv.z + (q.z - xv.z); r.w = xv.w + (q.w - xv.w);
        *(float4*)(o0 + (size_t)d * HW_) = r;
        *(float4*)(o1 + (size_t)d * HW_) = q;
    }
}

extern "C" void kernel_launch(void* const* d_in, const int* in_sizes, int n_in,
                              void* d_out, int out_size, void* d_ws, size_t ws_size,
                              hipStream_t stream) {
    const float* x = (const float*)d_in[0];
    const float* E = (const float*)d_in[1];
    float* out = (float*)d_out;

    char* p = (char*)d_ws;
    ushort* xf = (ushort*)p;                 p += (size_t)N_ * D_ * 2;   // 8 MB
    ushort* ef = (ushort*)p;                 p += (size_t)K_ * D_ * 2;   // 4 MB
    float*  c  = (float*)p;                  p += (size_t)K_ * 4;
    float*  pd1 = (float*)p;                 p += (size_t)NB_ * N_ * 4;  // 2 MB
    int*    pi1 = (int*)p;                   p += (size_t)NB_ * N_ * 4;
    float*  pd2 = (float*)p;                 p += (size_t)NB_ * N_ * 4;
    int*    idx = (int*)p;                   p += (size_t)N_ * 4;
    unsigned long long* key = (unsigned long long*)p; p += (size_t)N_ * 8;
    unsigned int* pairs = (unsigned int*)p;  p += (size_t)524288 * 4;    // 2 MB cap
    unsigned int* scans = (unsigned int*)p;  p += (size_t)524288 * 4;    // 2 MB cap
    int*    counters = (int*)p;              p += 256;

    cnorm_kernel<<<K_ / 32, 256, 0, stream>>>(E, c, counters);
    prep_x<<<dim3(32, 8, 16), 256, 0, stream>>>(x, xf);
    prep_e<<<dim3(256, 8), 256, 0, stream>>>(E, ef);
    mfma_kernel<<<8192, 256, 0, stream>>>(xf, ef, c, pd1, pi1, pd2);
    merge_flag<<<N_ / 256, 256, 0, stream>>>(pd1, pi1, pd2, idx, counters, key, pairs, scans);
    recheck<<<384, 256, 0, stream>>>(x, E, c, pairs, scans, counters, key);
    write_kernel<<<N_ / 64, 256, 0, stream>>>(x, E, idx, key, out);
}